// Round 17
// baseline (120.032 us; speedup 1.0000x reference)
//
#include <hip/hip_runtime.h>
#include <hip/hip_bf16.h>

#define CNUM 100
#define NS   8192
#define DIM  768
#define BF   1024
#define SP   12288   // padded sample stride: >= NS + CNUM*31 (=11292), mult of 128
#define PHI_SZ ((size_t)CNUM * BF * BF)
#define MU_SZ  ((size_t)CNUM * BF)

typedef float f32x4 __attribute__((ext_vector_type(4)));
typedef short s16x8 __attribute__((ext_vector_type(8)));

// async global->LDS, 16B per lane; dest must be wave-uniform base + lane*16 (linear LDS)
#define GL2LDS(gp, lp) __builtin_amdgcn_global_load_lds( \
    (const __attribute__((address_space(1))) void*)(gp), \
    (__attribute__((address_space(3))) void*)(lp), 16, 0, 0)

// counted-vmcnt barrier pair (T3/T4): wait only own current-tile loads, keep
// next tile's in flight across the barrier; raw s_barrier (no implicit drain).
#define WAITV4 do { asm volatile("s_waitcnt vmcnt(4)" ::: "memory"); } while (0)
#define WAITV6 do { asm volatile("s_waitcnt vmcnt(6)" ::: "memory"); } while (0)
#define WAITV0 do { asm volatile("s_waitcnt vmcnt(0)" ::: "memory"); } while (0)

static __device__ __forceinline__ unsigned short f2bf(float x) {
  union { float f; unsigned int u; } v; v.f = x;
  unsigned int lsb = (v.u >> 16) & 1;
  v.u += 0x7fffu + lsb;                 // round-to-nearest-even
  return (unsigned short)(v.u >> 16);
}

static __device__ __forceinline__ float bf2f(unsigned short u) {
  return __uint_as_float(((unsigned int)u) << 16);
}

#define NCVT (NS * DIM / 4 / 256)        // 6144 X-convert blocks
#define NWT  ((DIM / 32) * (BF / 32))    // 768 W-transpose blocks

// ---------------- cvt (+prep in block 0): X->bf16, W->WT, hist/prefix/scatter ----------------

__global__ __launch_bounds__(256) void k_cvt(
    const float* __restrict__ X, unsigned short* __restrict__ Xbf,
    const float* __restrict__ W, unsigned short* __restrict__ WT,
    const int* __restrict__ lab, int* __restrict__ sIdx, int* __restrict__ poff,
    float* __restrict__ outCounts, unsigned short* __restrict__ zeroPad)
{
  __shared__ union {
    float tile[32][33];
    struct { int hw[4][104]; int wb[4][104]; int rk[4][104]; int off[CNUM + 1]; } p;
  } sm;
  const int b = blockIdx.x;
  const int t = threadIdx.x;
  if (b == 0) {
    // ---- prep: wave-privatized hist + prefix + scatter (4 waves x 2048 samples) ----
    const int w = t >> 6, l = t & 63;
    for (int i = t; i < 4 * 104; i += 256) { (&sm.p.hw[0][0])[i] = 0; (&sm.p.rk[0][0])[i] = 0; }
    __syncthreads();
    int myLab[32];
#pragma unroll
    for (int p = 0; p < 32; ++p)
      myLab[p] = lab[w * 2048 + p * 64 + l];     // 32 independent loads, batched
#pragma unroll
    for (int p = 0; p < 32; ++p)
      atomicAdd(&sm.p.hw[w][myLab[p]], 1);
    for (int i = t; i < SP; i += 256) sIdx[i] = -1;
    for (int i = t; i < DIM; i += 256) zeroPad[i] = 0;
    __syncthreads();
    if (t < CNUM) {                                // scan the 4 wave-hists for class t
      int base = 0;
#pragma unroll
      for (int ww = 0; ww < 4; ++ww) { sm.p.wb[ww][t] = base; base += sm.p.hw[ww][t]; }
      sm.p.hw[0][t] = base;                        // total count of class t
    }
    __syncthreads();
    if (t == 0) {
      int a = 0;
      for (int c = 0; c < CNUM; ++c) { sm.p.off[c] = a; a += (sm.p.hw[0][c] + 31) & ~31; }
      sm.p.off[CNUM] = a;
    }
    __syncthreads();
    if (t < CNUM) outCounts[t] = (float)sm.p.hw[0][t];
    if (t <= CNUM) poff[t] = sm.p.off[t];
#pragma unroll
    for (int p = 0; p < 32; ++p) {
      const int n = w * 2048 + p * 64 + l;
      const int c = myLab[p];
      const int r = atomicAdd(&sm.p.rk[w][c], 1);
      sIdx[sm.p.off[c] + sm.p.wb[w][c] + r] = n;   // fire-and-forget scattered store
    }
  } else if (b <= NCVT) {
    size_t i = ((size_t)(b - 1) * 256 + t) * 4;
    f32x4 v = __builtin_nontemporal_load((const f32x4*)(X + i));  // X read-once
    *(ushort4*)(Xbf + i) = make_ushort4(f2bf(v[0]), f2bf(v[1]), f2bf(v[2]), f2bf(v[3]));
  } else {
    const int bb = b - 1 - NCVT;
    const int kb = (bb % (DIM / 32)) * 32;
    const int fb = (bb / (DIM / 32)) * 32;
    {
      const int cc = t & 31, r4 = t >> 5;
#pragma unroll
      for (int i = 0; i < 4; ++i) {
        int r = r4 * 4 + i;
        sm.tile[r][cc] = W[(size_t)(kb + r) * BF + fb + cc];
      }
    }
    __syncthreads();
    {
      const int kc = t & 31, f4 = t >> 5;
#pragma unroll
      for (int i = 0; i < 4; ++i) {
        int fr = f4 * 4 + i;
        WT[(size_t)(fb + fr) * DIM + kb + kc] = f2bf(sm.tile[kc][fr]);
      }
    }
  }
}

// ---------------- GEMM1: featT[f][s] = relu( Xbf[sIdx[s]] @ W )[f], bf16 ----------------
// gload_lds staging, 2-deep counted-vmcnt pipeline; XCD chunked swizzle.

__global__ __launch_bounds__(256) void k_gemm1(
    const unsigned short* __restrict__ Xbf,  // [NS][DIM] bf16
    const unsigned short* __restrict__ WT,   // [BF][DIM] bf16
    const int* __restrict__ sIdx,            // [SP], -1 = pad
    const unsigned short* __restrict__ zeroPad,
    unsigned short* __restrict__ featT)      // [BF][SP] bf16
{
  __shared__ __align__(16) unsigned short As[2][128][32];  // 2 x 8 KB
  __shared__ __align__(16) unsigned short Bs[2][128][32];

  const int t = threadIdx.x;
  const int bid = blockIdx.x;                    // 768 blocks
  const int o = (bid & 7) * 96 + (bid >> 3);     // XCD chunk swizzle (768%8==0, bijective)
  const int f0 = (o & 7) * 128;
  const int s0 = (o >> 3) * 128;
  const int lane = t & 63;
  const int wave = t >> 6;
  const int wr = wave >> 1, wc = wave & 1;

  const int rr = t >> 2, qp = t & 3;
  const int rA0 = rr, rA1 = 64 + rr;
  const int qg0 = qp ^ ((rA0 >> 1) & 3);
  const int qg1 = qp ^ ((rA1 >> 1) & 3);
  const int n0 = sIdx[s0 + rA0];
  const int n1 = sIdx[s0 + rA1];
  const unsigned short* aSrc0 = (n0 >= 0 ? Xbf + (size_t)n0 * DIM : zeroPad) + qg0 * 8;
  const unsigned short* aSrc1 = (n1 >= 0 ? Xbf + (size_t)n1 * DIM : zeroPad) + qg1 * 8;
  const unsigned short* bSrc0 = WT + (size_t)(f0 + rA0) * DIM + qg0 * 8;
  const unsigned short* bSrc1 = WT + (size_t)(f0 + rA1) * DIM + qg1 * 8;
  unsigned short* aD = &As[0][0][0] + t * 8;   // + buf*4096 elems for buf 1
  unsigned short* bD = &Bs[0][0][0] + t * 8;

#define STAGE1(buf, kt) do {                      \
    const int o2 = (kt) * 32;                     \
    unsigned short* ad = aD + (buf) * 4096;       \
    unsigned short* bd = bD + (buf) * 4096;       \
    GL2LDS(aSrc0 + o2, ad);                       \
    GL2LDS(aSrc1 + o2, ad + 2048);                \
    GL2LDS(bSrc0 + o2, bd);                       \
    GL2LDS(bSrc1 + o2, bd + 2048);                \
  } while (0)

  f32x4 acc[4][4];
#pragma unroll
  for (int m = 0; m < 4; ++m)
#pragma unroll
    for (int q = 0; q < 4; ++q) acc[m][q] = (f32x4)0.0f;

  STAGE1(0, 0);
  STAGE1(1, 1);
  int cur = 0;
  for (int kt = 0; kt < DIM / 32; ++kt) {
    if (kt + 1 < DIM / 32) WAITV4; else WAITV0;    // own tile-kt loads done; kt+1 in flight
    __builtin_amdgcn_sched_barrier(0);
    __builtin_amdgcn_s_barrier();                  // all waves' tile-kt data resident

    s16x8 a[4], b[4];
#pragma unroll
    for (int m = 0; m < 4; ++m) {
      const int row = wr * 64 + m * 16 + (lane & 15);
      const int sq = (lane >> 4) ^ ((row >> 1) & 3);
      a[m] = *(const s16x8*)((const char*)As + cur * 8192 + row * 64 + sq * 16);
    }
#pragma unroll
    for (int q = 0; q < 4; ++q) {
      const int row = wc * 64 + q * 16 + (lane & 15);
      const int sq = (lane >> 4) ^ ((row >> 1) & 3);
      b[q] = *(const s16x8*)((const char*)Bs + cur * 8192 + row * 64 + sq * 16);
    }
#pragma unroll
    for (int m = 0; m < 4; ++m)
#pragma unroll
      for (int q = 0; q < 4; ++q)
        acc[m][q] = __builtin_amdgcn_mfma_f32_16x16x32_bf16(a[m], b[q], acc[m][q], 0, 0, 0);

    __builtin_amdgcn_sched_barrier(0);
    __builtin_amdgcn_s_barrier();                  // all reads of buf cur done
    if (kt + 2 < DIM / 32) STAGE1(cur, kt + 2);    // overwrite cur with tile kt+2
    cur ^= 1;
  }

  // epilogue: relu + bf16, transposed store into featT[f][s]
  const int rbase = s0 + wr * 64 + ((lane >> 4) << 2);
  const int cbase = f0 + wc * 64 + (lane & 15);
#pragma unroll
  for (int m = 0; m < 4; ++m) {
#pragma unroll
    for (int q = 0; q < 4; ++q) {
      f32x4 v = acc[m][q];
      unsigned short p0 = f2bf(fmaxf(v[0], 0.f));
      unsigned short p1 = f2bf(fmaxf(v[1], 0.f));
      unsigned short p2 = f2bf(fmaxf(v[2], 0.f));
      unsigned short p3 = f2bf(fmaxf(v[3], 0.f));
      const int s = rbase + m * 16;
      const int f = cbase + q * 16;
      *(ushort4*)(featT + (size_t)f * SP + s) = make_ushort4(p0, p1, p2, p3);
    }
  }
}

// ---------------- phi (+mu on diag blocks): 128x256 tiles, XCD-class-chunk swizzled ----------------
// One K-loop feeds 2x output vs R16: per-byte barriers/staging/prologue halved;
// A-staging traffic -25%. 2-deep counted-vmcnt (6 loads/tile -> vmcnt(6)); epilogue
// tbuf[32][260] transpose + 1KB-per-wave-inst full-line nontemporal stores.

#define NPHI (CNUM * 32)

__global__ __launch_bounds__(256, 2) void k_phi(
    const unsigned short* __restrict__ featT,
    const int* __restrict__ poff,
    float* __restrict__ out, float* __restrict__ mu)
{
  const int bid = blockIdx.x;
  const int t = threadIdx.x;
  const int lane = t & 63;
  const int wave = t >> 6;

  // 48 KB shared: K-loop As[2][128][32] @0 (16KB) + Bs[2][256][32] @16K (32KB);
  // epilogue reuses as tbuf[32][260] (33.3 KB)
  __shared__ __align__(16) char smem[49152];
  unsigned short* AsB = (unsigned short*)smem;
  unsigned short* BsB = (unsigned short*)(smem + 16384);
  float (*tbuf)[260] = (float(*)[260])smem;

  const int o = (bid & 7) * 400 + (bid >> 3);   // XCD class-chunk swizzle (3200%8==0)
  const int c = o >> 5;
  const int t32 = o & 31;
  const int i0 = (t32 >> 2) * 128;
  const int j0 = (t32 & 3) * 256;
  const bool diag = (t32 & 3) == (t32 >> 3);    // each i-tile counted once (j = i>>1)
  const int wr = wave >> 1, wc = wave & 1;

  const int kb0 = poff[c];
  const int ksteps = (poff[c + 1] - kb0) >> 5;

  const int rr = t >> 2, qp = t & 3;
  const int qgA0 = qp ^ ((rr >> 1) & 3);            // rows rr and 64+rr, 128+rr, 192+rr:
  const int qgA1 = qp ^ (((64 + rr) >> 1) & 3);     // (row>>1)&3 depends only on rr (64 mult of 8)
  const unsigned short* aSrc0 = featT + (size_t)(i0 + rr) * SP + kb0 + qgA0 * 8;
  const unsigned short* aSrc1 = featT + (size_t)(i0 + 64 + rr) * SP + kb0 + qgA1 * 8;
  const unsigned short* bSrc0 = featT + (size_t)(j0 + rr) * SP + kb0 + qgA0 * 8;
  const unsigned short* bSrc1 = featT + (size_t)(j0 + 64 + rr) * SP + kb0 + qgA1 * 8;
  const unsigned short* bSrc2 = featT + (size_t)(j0 + 128 + rr) * SP + kb0 + qgA0 * 8;
  const unsigned short* bSrc3 = featT + (size_t)(j0 + 192 + rr) * SP + kb0 + qgA1 * 8;
  unsigned short* aD = AsB + t * 8;              // A buf stride 4096 elems (8KB)
  unsigned short* bD = BsB + t * 8;              // B buf stride 8192 elems (16KB)

#define STAGE2(buf, kt) do {                      \
    const int o2 = (kt) * 32;                     \
    unsigned short* ad = aD + (buf) * 4096;       \
    unsigned short* bd = bD + (buf) * 8192;       \
    GL2LDS(aSrc0 + o2, ad);                       \
    GL2LDS(aSrc1 + o2, ad + 2048);                \
    GL2LDS(bSrc0 + o2, bd);                       \
    GL2LDS(bSrc1 + o2, bd + 2048);                \
    GL2LDS(bSrc2 + o2, bd + 4096);                \
    GL2LDS(bSrc3 + o2, bd + 6144);                \
  } while (0)

  f32x4 acc[4][8];
#pragma unroll
  for (int m = 0; m < 4; ++m)
#pragma unroll
    for (int q = 0; q < 8; ++q) acc[m][q] = (f32x4)0.0f;

  float msum = 0.f;                               // mu partial (diag blocks)
  const int mrow = t >> 1;                        // mu: this thread's A-row
  const int mhalf = t & 1;                        // mu: which 16-elem half

  if (ksteps > 0) STAGE2(0, 0);
  if (ksteps > 1) STAGE2(1, 1);
  int cur = 0;
#pragma unroll 1
  for (int kt = 0; kt < ksteps; ++kt) {
    if (kt + 1 < ksteps) WAITV6; else WAITV0;      // own tile-kt (6 loads) done; kt+1 in flight
    __builtin_amdgcn_sched_barrier(0);
    __builtin_amdgcn_s_barrier();                  // all waves' tile-kt data resident

    s16x8 a[4], b[8];
#pragma unroll
    for (int m = 0; m < 4; ++m) {
      const int row = wr * 64 + m * 16 + (lane & 15);
      const int sq = (lane >> 4) ^ ((row >> 1) & 3);
      a[m] = *(const s16x8*)((const char*)AsB + cur * 8192 + row * 64 + sq * 16);
    }
#pragma unroll
    for (int q = 0; q < 8; ++q) {
      const int row = wc * 128 + q * 16 + (lane & 15);
      const int sq = (lane >> 4) ^ ((row >> 1) & 3);
      b[q] = *(const s16x8*)((const char*)BsB + cur * 16384 + row * 64 + sq * 16);
    }
#pragma unroll
    for (int m = 0; m < 4; ++m)
#pragma unroll
      for (int q = 0; q < 8; ++q)
        acc[m][q] = __builtin_amdgcn_mfma_f32_16x16x32_bf16(a[m], b[q], acc[m][q], 0, 0, 0);

    if (diag) {
      // mu: sum this thread's 16 bf16 of A row mrow (k-order irrelevant for a sum)
      const char* rbp = (const char*)AsB + cur * 8192 + mrow * 64 + mhalf * 32;
      s16x8 u0 = *(const s16x8*)rbp;
      s16x8 u1 = *(const s16x8*)(rbp + 16);
#pragma unroll
      for (int e = 0; e < 8; ++e)
        msum += bf2f((unsigned short)u0[e]) + bf2f((unsigned short)u1[e]);
    }

    __builtin_amdgcn_sched_barrier(0);
    __builtin_amdgcn_s_barrier();                  // all reads of buf cur done
    if (kt + 2 < ksteps) STAGE2(cur, kt + 2);      // overwrite cur with tile kt+2
    cur ^= 1;
  }

  if (diag) {
    const float other = __shfl_xor(msum, 1, 64);   // partner half (t^1, same wave)
    if (mhalf == 0) mu[(size_t)c * BF + i0 + mrow] = msum + other;
  }

  // ---- epilogue: per-m LDS transpose -> full-line nontemporal f32x4 stores ----
  // readers: full wave covers one 256-float row (1KB/inst, whole 128B lines)
  float* phiC = out + (size_t)c * (BF * BF);
  const int s4   = (lane >> 4) << 2;            // fragment sub-row base 0,4,8,12
  const int lrow = wr * 16 + s4;                // writer: tbuf row base
  const int lcol = wc * 128 + (lane & 15);      // writer: tbuf col base
  const int rcol = lane * 4;                    // reader: col (floats)
  const int rr4  = t >> 6;                      // reader: row within 4-row group
#pragma unroll
  for (int m = 0; m < 4; ++m) {
    __syncthreads();                            // tbuf free (K-loop done / prev m read)
#pragma unroll
    for (int q = 0; q < 8; ++q) {
      f32x4 v = acc[m][q];
#pragma unroll
      for (int r = 0; r < 4; ++r)
        tbuf[lrow + r][lcol + q * 16] = v[r];
    }
    __syncthreads();
#pragma unroll
    for (int u = 0; u < 8; ++u) {
      const int r = u * 4 + rr4;                // tbuf row 0..31
      const int grow = i0 + (r >> 4) * 64 + m * 16 + (r & 15);
      f32x4 val = *(const f32x4*)&tbuf[r][rcol];
      __builtin_nontemporal_store(val, (f32x4*)(phiC + (size_t)grow * BF + j0 + rcol));
    }
  }
}

// ---------------- launch ----------------

extern "C" void kernel_launch(void* const* d_in, const int* in_sizes, int n_in,
                              void* d_out, int out_size, void* d_ws, size_t ws_size,
                              hipStream_t stream) {
  const float* X = (const float*)d_in[0];
  const float* W = (const float*)d_in[1];
  const int* lab = (const int*)d_in[2];
  float* out = (float*)d_out;
  char* ws = (char*)d_ws;

  int* poff = (int*)(ws);                                   // (CNUM+1) ints
  int* sIdx = (int*)(ws + 1024);                            // SP ints
  unsigned short* zeroPad = (unsigned short*)(ws + 1024 + SP * 4);  // DIM bf16 zeros
  unsigned short* featT = (unsigned short*)(ws + 65536);    // BF*SP bf16
  unsigned short* Xbf = (unsigned short*)(ws + 65536 + (size_t)BF * SP * 2);
  unsigned short* WT  = (unsigned short*)(ws + 65536 + (size_t)BF * SP * 2 + (size_t)NS * DIM * 2);

  k_cvt<<<1 + NCVT + NWT, 256, 0, stream>>>(X, Xbf, W, WT, lab, sIdx, poff,
                                            out + PHI_SZ + MU_SZ, zeroPad);
  k_gemm1<<<768, 256, 0, stream>>>(Xbf, WT, sIdx, zeroPad, featT);
  k_phi<<<NPHI, 256, 0, stream>>>(featT, poff, out, out + (size_t)PHI_SZ);
}

// Round 18
// 116.433 us; speedup vs baseline: 1.0309x; 1.0309x over previous
//
#include <hip/hip_runtime.h>
#include <hip/hip_bf16.h>

#define CNUM 100
#define NS   8192
#define DIM  768
#define BF   1024
#define SP   12288   // padded sample stride: >= NS + CNUM*31 (=11292), mult of 128
#define PHI_SZ ((size_t)CNUM * BF * BF)
#define MU_SZ  ((size_t)CNUM * BF)

typedef float f32x4 __attribute__((ext_vector_type(4)));
typedef short s16x8 __attribute__((ext_vector_type(8)));

// async global->LDS, 16B per lane; dest must be wave-uniform base + lane*16 (linear LDS)
#define GL2LDS(gp, lp) __builtin_amdgcn_global_load_lds( \
    (const __attribute__((address_space(1))) void*)(gp), \
    (__attribute__((address_space(3))) void*)(lp), 16, 0, 0)

// counted-vmcnt barrier pair (T3/T4): wait only own current-tile loads, keep
// next tile's in flight across the barrier; raw s_barrier (no implicit drain).
#define WAITV4 do { asm volatile("s_waitcnt vmcnt(4)" ::: "memory"); } while (0)
#define WAITV0 do { asm volatile("s_waitcnt vmcnt(0)" ::: "memory"); } while (0)

static __device__ __forceinline__ unsigned short f2bf(float x) {
  union { float f; unsigned int u; } v; v.f = x;
  unsigned int lsb = (v.u >> 16) & 1;
  v.u += 0x7fffu + lsb;                 // round-to-nearest-even
  return (unsigned short)(v.u >> 16);
}

static __device__ __forceinline__ float bf2f(unsigned short u) {
  return __uint_as_float(((unsigned int)u) << 16);
}

#define NCVT (NS * DIM / 4 / 256)        // 6144 X-convert blocks
#define NWT  ((DIM / 32) * (BF / 32))    // 768 W-transpose blocks

// ---------------- cvt (+prep in block 0): X->bf16, W->WT, hist/prefix/scatter ----------------

__global__ __launch_bounds__(256) void k_cvt(
    const float* __restrict__ X, unsigned short* __restrict__ Xbf,
    const float* __restrict__ W, unsigned short* __restrict__ WT,
    const int* __restrict__ lab, int* __restrict__ sIdx, int* __restrict__ poff,
    float* __restrict__ outCounts, unsigned short* __restrict__ zeroPad)
{
  __shared__ union {
    float tile[32][33];
    struct { int hw[4][104]; int wb[4][104]; int rk[4][104]; int off[CNUM + 1]; } p;
  } sm;
  const int b = blockIdx.x;
  const int t = threadIdx.x;
  if (b == 0) {
    // ---- prep: wave-privatized hist + prefix + scatter (4 waves x 2048 samples) ----
    const int w = t >> 6, l = t & 63;
    for (int i = t; i < 4 * 104; i += 256) { (&sm.p.hw[0][0])[i] = 0; (&sm.p.rk[0][0])[i] = 0; }
    __syncthreads();
    int myLab[32];
#pragma unroll
    for (int p = 0; p < 32; ++p)
      myLab[p] = lab[w * 2048 + p * 64 + l];     // 32 independent loads, batched
#pragma unroll
    for (int p = 0; p < 32; ++p)
      atomicAdd(&sm.p.hw[w][myLab[p]], 1);
    for (int i = t; i < SP; i += 256) sIdx[i] = -1;
    for (int i = t; i < DIM; i += 256) zeroPad[i] = 0;
    __syncthreads();
    if (t < CNUM) {                                // scan the 4 wave-hists for class t
      int base = 0;
#pragma unroll
      for (int ww = 0; ww < 4; ++ww) { sm.p.wb[ww][t] = base; base += sm.p.hw[ww][t]; }
      sm.p.hw[0][t] = base;                        // total count of class t
    }
    __syncthreads();
    if (t == 0) {
      int a = 0;
      for (int c = 0; c < CNUM; ++c) { sm.p.off[c] = a; a += (sm.p.hw[0][c] + 31) & ~31; }
      sm.p.off[CNUM] = a;
    }
    __syncthreads();
    if (t < CNUM) outCounts[t] = (float)sm.p.hw[0][t];
    if (t <= CNUM) poff[t] = sm.p.off[t];
#pragma unroll
    for (int p = 0; p < 32; ++p) {
      const int n = w * 2048 + p * 64 + l;
      const int c = myLab[p];
      const int r = atomicAdd(&sm.p.rk[w][c], 1);
      sIdx[sm.p.off[c] + sm.p.wb[w][c] + r] = n;   // fire-and-forget scattered store
    }
  } else if (b <= NCVT) {
    size_t i = ((size_t)(b - 1) * 256 + t) * 4;
    f32x4 v = __builtin_nontemporal_load((const f32x4*)(X + i));  // X read-once
    *(ushort4*)(Xbf + i) = make_ushort4(f2bf(v[0]), f2bf(v[1]), f2bf(v[2]), f2bf(v[3]));
  } else {
    const int bb = b - 1 - NCVT;
    const int kb = (bb % (DIM / 32)) * 32;
    const int fb = (bb / (DIM / 32)) * 32;
    {
      const int cc = t & 31, r4 = t >> 5;
#pragma unroll
      for (int i = 0; i < 4; ++i) {
        int r = r4 * 4 + i;
        sm.tile[r][cc] = W[(size_t)(kb + r) * BF + fb + cc];
      }
    }
    __syncthreads();
    {
      const int kc = t & 31, f4 = t >> 5;
#pragma unroll
      for (int i = 0; i < 4; ++i) {
        int fr = f4 * 4 + i;
        WT[(size_t)(fb + fr) * DIM + kb + kc] = f2bf(sm.tile[kc][fr]);
      }
    }
  }
}

// ---------------- GEMM1: featT[f][s] = relu( Xbf[sIdx[s]] @ W )[f], bf16 ----------------
// gload_lds staging, 2-deep counted-vmcnt pipeline; XCD chunked swizzle.

__global__ __launch_bounds__(256) void k_gemm1(
    const unsigned short* __restrict__ Xbf,  // [NS][DIM] bf16
    const unsigned short* __restrict__ WT,   // [BF][DIM] bf16
    const int* __restrict__ sIdx,            // [SP], -1 = pad
    const unsigned short* __restrict__ zeroPad,
    unsigned short* __restrict__ featT)      // [BF][SP] bf16
{
  __shared__ __align__(16) unsigned short As[2][128][32];  // 2 x 8 KB
  __shared__ __align__(16) unsigned short Bs[2][128][32];

  const int t = threadIdx.x;
  const int bid = blockIdx.x;                    // 768 blocks
  const int o = (bid & 7) * 96 + (bid >> 3);     // XCD chunk swizzle (768%8==0, bijective)
  const int f0 = (o & 7) * 128;
  const int s0 = (o >> 3) * 128;
  const int lane = t & 63;
  const int wave = t >> 6;
  const int wr = wave >> 1, wc = wave & 1;

  const int rr = t >> 2, qp = t & 3;
  const int rA0 = rr, rA1 = 64 + rr;
  const int qg0 = qp ^ ((rA0 >> 1) & 3);
  const int qg1 = qp ^ ((rA1 >> 1) & 3);
  const int n0 = sIdx[s0 + rA0];
  const int n1 = sIdx[s0 + rA1];
  const unsigned short* aSrc0 = (n0 >= 0 ? Xbf + (size_t)n0 * DIM : zeroPad) + qg0 * 8;
  const unsigned short* aSrc1 = (n1 >= 0 ? Xbf + (size_t)n1 * DIM : zeroPad) + qg1 * 8;
  const unsigned short* bSrc0 = WT + (size_t)(f0 + rA0) * DIM + qg0 * 8;
  const unsigned short* bSrc1 = WT + (size_t)(f0 + rA1) * DIM + qg1 * 8;
  unsigned short* aD = &As[0][0][0] + t * 8;   // + buf*4096 elems for buf 1
  unsigned short* bD = &Bs[0][0][0] + t * 8;

#define STAGE1(buf, kt) do {                      \
    const int o2 = (kt) * 32;                     \
    unsigned short* ad = aD + (buf) * 4096;       \
    unsigned short* bd = bD + (buf) * 4096;       \
    GL2LDS(aSrc0 + o2, ad);                       \
    GL2LDS(aSrc1 + o2, ad + 2048);                \
    GL2LDS(bSrc0 + o2, bd);                       \
    GL2LDS(bSrc1 + o2, bd + 2048);                \
  } while (0)

  f32x4 acc[4][4];
#pragma unroll
  for (int m = 0; m < 4; ++m)
#pragma unroll
    for (int q = 0; q < 4; ++q) acc[m][q] = (f32x4)0.0f;

  STAGE1(0, 0);
  STAGE1(1, 1);
  int cur = 0;
  for (int kt = 0; kt < DIM / 32; ++kt) {
    if (kt + 1 < DIM / 32) WAITV4; else WAITV0;    // own tile-kt loads done; kt+1 in flight
    __builtin_amdgcn_sched_barrier(0);
    __builtin_amdgcn_s_barrier();                  // all waves' tile-kt data resident

    s16x8 a[4], b[4];
#pragma unroll
    for (int m = 0; m < 4; ++m) {
      const int row = wr * 64 + m * 16 + (lane & 15);
      const int sq = (lane >> 4) ^ ((row >> 1) & 3);
      a[m] = *(const s16x8*)((const char*)As + cur * 8192 + row * 64 + sq * 16);
    }
#pragma unroll
    for (int q = 0; q < 4; ++q) {
      const int row = wc * 64 + q * 16 + (lane & 15);
      const int sq = (lane >> 4) ^ ((row >> 1) & 3);
      b[q] = *(const s16x8*)((const char*)Bs + cur * 8192 + row * 64 + sq * 16);
    }
#pragma unroll
    for (int m = 0; m < 4; ++m)
#pragma unroll
      for (int q = 0; q < 4; ++q)
        acc[m][q] = __builtin_amdgcn_mfma_f32_16x16x32_bf16(a[m], b[q], acc[m][q], 0, 0, 0);

    __builtin_amdgcn_sched_barrier(0);
    __builtin_amdgcn_s_barrier();                  // all reads of buf cur done
    if (kt + 2 < DIM / 32) STAGE1(cur, kt + 2);    // overwrite cur with tile kt+2
    cur ^= 1;
  }

  // epilogue: relu + bf16, transposed store into featT[f][s]
  const int rbase = s0 + wr * 64 + ((lane >> 4) << 2);
  const int cbase = f0 + wc * 64 + (lane & 15);
#pragma unroll
  for (int m = 0; m < 4; ++m) {
#pragma unroll
    for (int q = 0; q < 4; ++q) {
      f32x4 v = acc[m][q];
      unsigned short p0 = f2bf(fmaxf(v[0], 0.f));
      unsigned short p1 = f2bf(fmaxf(v[1], 0.f));
      unsigned short p2 = f2bf(fmaxf(v[2], 0.f));
      unsigned short p3 = f2bf(fmaxf(v[3], 0.f));
      const int s = rbase + m * 16;
      const int f = cbase + q * 16;
      *(ushort4*)(featT + (size_t)f * SP + s) = make_ushort4(p0, p1, p2, p3);
    }
  }
}

// ---------------- phi (+mu folded into diagonal blocks), XCD-class-chunk swizzled ----------------
// K-loop: 2-deep counted-vmcnt (R12). Epilogue: per-m LDS transpose + full-line
// nontemporal f32x4 stores (R14). Diagonal blocks (i0==j0) additionally accumulate
// mu[c][i0..i0+127] from the As tile while it is resident between the two barriers.
// 128x128 tile / 32KB LDS / ~5 blocks per CU: best measured configuration (R16).

#define NPHI (CNUM * 64)

__global__ __launch_bounds__(256) void k_phi(
    const unsigned short* __restrict__ featT,
    const int* __restrict__ poff,
    float* __restrict__ out, float* __restrict__ mu)
{
  const int bid = blockIdx.x;
  const int t = threadIdx.x;
  const int lane = t & 63;
  const int wave = t >> 6;

  // 32 KB shared: K-loop uses As/Bs; epilogue reuses as tbuf[32][132]
  __shared__ __align__(16) char smem[32768];
  unsigned short* AsB = (unsigned short*)smem;            // As[2][128][32], 16 KB
  unsigned short* BsB = (unsigned short*)(smem + 16384);  // Bs[2][128][32], 16 KB
  float (*tbuf)[132] = (float(*)[132])smem;

  const int o = (bid & 7) * 800 + (bid >> 3);   // XCD class-chunk swizzle (6400%8==0)
  const int c = o >> 6;
  const int t64 = o & 63;
  const int i0 = (t64 >> 3) * 128;
  const int j0 = (t64 & 7) * 128;
  const bool diag = (t64 >> 3) == (t64 & 7);    // block-uniform
  const int wr = wave >> 1, wc = wave & 1;

  const int kb0 = poff[c];
  const int ksteps = (poff[c + 1] - kb0) >> 5;

  const int rr = t >> 2, qp = t & 3;
  const int rA0 = rr, rA1 = 64 + rr;
  const int qg0 = qp ^ ((rA0 >> 1) & 3);
  const int qg1 = qp ^ ((rA1 >> 1) & 3);
  const unsigned short* aSrc0 = featT + (size_t)(i0 + rA0) * SP + kb0 + qg0 * 8;
  const unsigned short* aSrc1 = featT + (size_t)(i0 + rA1) * SP + kb0 + qg1 * 8;
  const unsigned short* bSrc0 = featT + (size_t)(j0 + rA0) * SP + kb0 + qg0 * 8;
  const unsigned short* bSrc1 = featT + (size_t)(j0 + rA1) * SP + kb0 + qg1 * 8;
  unsigned short* aD = AsB + t * 8;
  unsigned short* bD = BsB + t * 8;

#define STAGE2(buf, kt) do {                      \
    const int o2 = (kt) * 32;                     \
    unsigned short* ad = aD + (buf) * 4096;       \
    unsigned short* bd = bD + (buf) * 4096;       \
    GL2LDS(aSrc0 + o2, ad);                       \
    GL2LDS(aSrc1 + o2, ad + 2048);                \
    GL2LDS(bSrc0 + o2, bd);                       \
    GL2LDS(bSrc1 + o2, bd + 2048);                \
  } while (0)

  f32x4 acc[4][4];
#pragma unroll
  for (int m = 0; m < 4; ++m)
#pragma unroll
    for (int q = 0; q < 4; ++q) acc[m][q] = (f32x4)0.0f;

  float msum = 0.f;                               // mu partial (diag blocks)
  const int mrow = t >> 1;                        // mu: this thread's A-row
  const int mhalf = t & 1;                        // mu: which 16-elem half

  if (ksteps > 0) STAGE2(0, 0);
  if (ksteps > 1) STAGE2(1, 1);
  int cur = 0;
#pragma unroll 1
  for (int kt = 0; kt < ksteps; ++kt) {
    if (kt + 1 < ksteps) WAITV4; else WAITV0;      // own tile-kt loads done; kt+1 in flight
    __builtin_amdgcn_sched_barrier(0);
    __builtin_amdgcn_s_barrier();                  // all waves' tile-kt data resident

    s16x8 a[4], b[4];
#pragma unroll
    for (int m = 0; m < 4; ++m) {
      const int row = wr * 64 + m * 16 + (lane & 15);
      const int sq = (lane >> 4) ^ ((row >> 1) & 3);
      a[m] = *(const s16x8*)((const char*)AsB + cur * 8192 + row * 64 + sq * 16);
    }
#pragma unroll
    for (int q = 0; q < 4; ++q) {
      const int row = wc * 64 + q * 16 + (lane & 15);
      const int sq = (lane >> 4) ^ ((row >> 1) & 3);
      b[q] = *(const s16x8*)((const char*)BsB + cur * 8192 + row * 64 + sq * 16);
    }
#pragma unroll
    for (int m = 0; m < 4; ++m)
#pragma unroll
      for (int q = 0; q < 4; ++q)
        acc[m][q] = __builtin_amdgcn_mfma_f32_16x16x32_bf16(a[m], b[q], acc[m][q], 0, 0, 0);

    if (diag) {
      // mu: sum this thread's 16 bf16 of row mrow (k-order irrelevant for a sum)
      const char* rbp = (const char*)AsB + cur * 8192 + mrow * 64 + mhalf * 32;
      s16x8 u0 = *(const s16x8*)rbp;
      s16x8 u1 = *(const s16x8*)(rbp + 16);
#pragma unroll
      for (int e = 0; e < 8; ++e)
        msum += bf2f((unsigned short)u0[e]) + bf2f((unsigned short)u1[e]);
    }

    __builtin_amdgcn_sched_barrier(0);
    __builtin_amdgcn_s_barrier();                  // all reads of buf cur done
    if (kt + 2 < ksteps) STAGE2(cur, kt + 2);      // overwrite cur with tile kt+2
    cur ^= 1;
  }

  if (diag) {
    const float other = __shfl_xor(msum, 1, 64);   // partner half (t^1, same wave)
    if (mhalf == 0) mu[(size_t)c * BF + i0 + mrow] = msum + other;
  }

  // ---- epilogue: per-m LDS transpose -> full-line nontemporal f32x4 stores ----
  float* phiC = out + (size_t)c * (BF * BF);
  const int s4   = (lane >> 4) << 2;            // fragment sub-row base 0,4,8,12
  const int lrow = wr * 16 + s4;                // writer: tbuf row base
  const int lcol = wc * 64 + (lane & 15);       // writer: tbuf col base
  const int rcol = (t & 31) * 4;                // reader: col (floats); 32 lanes = 512B row
  const int rr8  = t >> 5;                      // reader: row within 8-row group
#pragma unroll
  for (int m = 0; m < 4; ++m) {
    __syncthreads();                            // tbuf free (K-loop done / prev m read)
#pragma unroll
    for (int q = 0; q < 4; ++q) {
      f32x4 v = acc[m][q];
#pragma unroll
      for (int r = 0; r < 4; ++r)
        tbuf[lrow + r][lcol + q * 16] = v[r];
    }
    __syncthreads();
#pragma unroll
    for (int u = 0; u < 4; ++u) {
      const int r = u * 8 + rr8;                // tbuf row 0..31
      const int grow = i0 + (r >> 4) * 64 + m * 16 + (r & 15);
      f32x4 val = *(const f32x4*)&tbuf[r][rcol];
      __builtin_nontemporal_store(val, (f32x4*)(phiC + (size_t)grow * BF + j0 + rcol));
    }
  }
}

// ---------------- launch ----------------

extern "C" void kernel_launch(void* const* d_in, const int* in_sizes, int n_in,
                              void* d_out, int out_size, void* d_ws, size_t ws_size,
                              hipStream_t stream) {
  const float* X = (const float*)d_in[0];
  const float* W = (const float*)d_in[1];
  const int* lab = (const int*)d_in[2];
  float* out = (float*)d_out;
  char* ws = (char*)d_ws;

  int* poff = (int*)(ws);                                   // (CNUM+1) ints
  int* sIdx = (int*)(ws + 1024);                            // SP ints
  unsigned short* zeroPad = (unsigned short*)(ws + 1024 + SP * 4);  // DIM bf16 zeros
  unsigned short* featT = (unsigned short*)(ws + 65536);    // BF*SP bf16
  unsigned short* Xbf = (unsigned short*)(ws + 65536 + (size_t)BF * SP * 2);
  unsigned short* WT  = (unsigned short*)(ws + 65536 + (size_t)BF * SP * 2 + (size_t)NS * DIM * 2);

  k_cvt<<<1 + NCVT + NWT, 256, 0, stream>>>(X, Xbf, W, WT, lab, sIdx, poff,
                                            out + PHI_SZ + MU_SZ, zeroPad);
  k_gemm1<<<768, 256, 0, stream>>>(Xbf, WT, sIdx, zeroPad, featT);
  k_phi<<<NPHI, 256, 0, stream>>>(featT, poff, out, out + (size_t)PHI_SZ);
}